// Round 2
// baseline (554.453 us; speedup 1.0000x reference)
//
#include <hip/hip_runtime.h>

// casConv2d: B=1, C=128, H=W=32, OC=128, K=3, pad=1, stride=1.
// L = 1024, CKK = 1152 = 36 exact 32-tap chunks (reference front-pad chunk == 0,
// contributes exactly 0 after fake-quant -> ignored).
//
// Round-10: FUSED single kernel, zero workspace.
// Evidence from R8/R9: two radically different fused_mq implementations landed
// within noise (74.9 vs 76.3 with the poison fill itself 3.5us slower in R9),
// so the mq stage was never ~25us; budget = ws-poison fill (43-47us, harness,
// at its HBM write roofline) + ~20us fixed harness restore overhead + only
// ~8-10us of app kernels (gemm ~4.5 + mq ~3 + inter-kernel drain + launch).
// The only controllable structure left is the two-kernel round trip itself:
// kill the 18.9MB intermediate (write+read), the dependent-launch drain, and
// one launch by computing everything in ONE kernel:
//   grid 256 blocks (1/CU) x 256 threads; block owns 4 px (one row segment),
//   thread owns (oc = t&127) x (px pair pp = t>>7). Per chunk j: stage W slice
//   16KB XOR-swizzled [oc][tap] (conflict-free ds_read_b128 per oc) + x slice
//   512B, double-buffered LDS, loads issued before compute (T14 issue-early).
//   Per-chunk partials v0[36]/v1[36] live in VGPRs (static unroll, rule #20),
//   so NO recompute. Epilogue: shfl minmax over oc -> scale/zp -> quantize the
//   register-held partials -> LDS transpose -> float4 stores.
// FP order is bit-identical to the passing R9 path: per-(oc,px,chunk) 32-tap
// ascending FMA chain, per-px total = Sum_j v[j] then +bias, minmax
// order-insensitive, identical quant ops (rintf/clip/trunc/NaN handling).
#define L_    1024
#define CKK_  1152
#define QMAX_ 255.0f
#define NCH   36

__global__ __launch_bounds__(256) void fused_cas(
    const float* __restrict__ x,      // [128][32][32]
    const float* __restrict__ w,      // [128][1152]
    const float* __restrict__ bias,   // [128]
    float* __restrict__ out)          // [128][1024]
{
    // W buffer: swizzled [oc][tap] rows of 32 floats (128B). Read as b128 at
    // float index oc*32 + 4*(k16 ^ (oc&7)) -> quarter-wave 2-way max (free).
    __shared__ __align__(16) float Wb[2][128 * 32];   // 2 x 16KB
    __shared__ __align__(16) float xs[2][32 * 4];     // [tap][px-local], 2 x 512B
    __shared__ float red[4][4];                       // per-wave {mn0,mx0,mn1,mx1}
    __shared__ float spar[2][2][3];                   // [pp][s]{sc,zp,iv}
    __shared__ float qb[4][128];                      // [px-local][oc]

    const int t   = threadIdx.x;
    const int b   = blockIdx.x;
    const int oc  = t & 127;
    const int pp  = t >> 7;            // waves 0,1 -> px {0,1}; waves 2,3 -> {2,3}
    const int ocm = oc & 7;
    const int oh  = b >> 3;            // all 4 px share one output row
    const int ow0 = (b & 7) * 4;
    const int l0  = b * 4;

    // ---- W staging addressing: 4 float4 per thread per chunk ----
    // f4 = it*256 + t ; oc_s = f4>>3 ; ks = f4&7 (tap quad)
    int wgo[4], wlo[4];
#pragma unroll
    for (int it = 0; it < 4; ++it) {
        const int f4   = it * 256 + t;
        const int oc_s = f4 >> 3, ks = f4 & 7;
        wgo[it] = oc_s * CKK_ + ks * 4;               // + j*32 at use
        wlo[it] = oc_s * 32 + 4 * (ks ^ (oc_s & 7));  // swizzled float index
    }
    // ---- x staging: one predicated scalar per thread (t<128) per chunk ----
    const int xtap = t >> 2, xll = t & 3;

    float v0[NCH], v1[NCH];            // per-chunk partials, statically indexed

    // ================= prologue: stage chunk 0 =================
    {
        float4 wr[4];
#pragma unroll
        for (int it = 0; it < 4; ++it)
            wr[it] = *(const float4*)(w + wgo[it]);
        float xr = 0.f;
        if (t < 128) {
            const int d  = xtap;                       // chunk 0
            const int c  = d / 9, r = d - 9 * c;
            const int kh = r / 3, kw = r - 3 * kh;
            const int iy = oh + kh - 1, ix = ow0 + xll + kw - 1;
            const bool ok = ((unsigned)iy < 32u) & ((unsigned)ix < 32u);
            const float vv = x[ok ? (c * 1024 + iy * 32 + ix) : 0];
            xr = ok ? vv : 0.f;
        }
#pragma unroll
        for (int it = 0; it < 4; ++it)
            *(float4*)(&Wb[0][wlo[it]]) = wr[it];
        if (t < 128) xs[0][xtap * 4 + xll] = xr;
        __syncthreads();
    }

    // ================= main chunk loop (fully unrolled) =================
#pragma unroll
    for (int j = 0; j < NCH; ++j) {
        const int cur = j & 1, nxt = cur ^ 1;

        // issue-early: loads for chunk j+1 before this chunk's compute
        float4 wr[4];
        float  xr = 0.f;
        if (j + 1 < NCH) {
#pragma unroll
            for (int it = 0; it < 4; ++it)
                wr[it] = *(const float4*)(w + wgo[it] + (j + 1) * 32);
            if (t < 128) {
                const int d  = (j + 1) * 32 + xtap;
                const int c  = d / 9, r = d - 9 * c;
                const int kh = r / 3, kw = r - 3 * kh;
                const int iy = oh + kh - 1, ix = ow0 + xll + kw - 1;
                const bool ok = ((unsigned)iy < 32u) & ((unsigned)ix < 32u);
                const float vv = x[ok ? (c * 1024 + iy * 32 + ix) : 0];
                xr = ok ? vv : 0.f;
            }
        }

        // compute chunk j: 32-tap ascending FMA chain per output
        float a0 = 0.f, a1 = 0.f;
        const float* Wp = &Wb[cur][oc * 32];
        const float* Xp = &xs[cur][2 * pp];
#pragma unroll
        for (int k16 = 0; k16 < 8; ++k16) {
            const float4 wv  = *(const float4*)(Wp + 4 * (k16 ^ ocm));
            const float2 xv0 = *(const float2*)(Xp + (k16 * 4 + 0) * 4);
            const float2 xv1 = *(const float2*)(Xp + (k16 * 4 + 1) * 4);
            const float2 xv2 = *(const float2*)(Xp + (k16 * 4 + 2) * 4);
            const float2 xv3 = *(const float2*)(Xp + (k16 * 4 + 3) * 4);
            a0 = fmaf(wv.x, xv0.x, a0); a1 = fmaf(wv.x, xv0.y, a1);
            a0 = fmaf(wv.y, xv1.x, a0); a1 = fmaf(wv.y, xv1.y, a1);
            a0 = fmaf(wv.z, xv2.x, a0); a1 = fmaf(wv.z, xv2.y, a1);
            a0 = fmaf(wv.w, xv3.x, a0); a1 = fmaf(wv.w, xv3.y, a1);
        }
        v0[j] = a0; v1[j] = a1;

        if (j + 1 < NCH) {
#pragma unroll
            for (int it = 0; it < 4; ++it)
                *(float4*)(&Wb[nxt][wlo[it]]) = wr[it];
            if (t < 128) xs[nxt][xtap * 4 + xll] = xr;
        }
        __syncthreads();
    }

    // ================= totals + per-px minmax =================
    float s0 = 0.f, s1 = 0.f;
#pragma unroll
    for (int j = 0; j < NCH; ++j) { s0 += v0[j]; s1 += v1[j]; }
    const float bval = bias[oc];
    const float t0 = s0 + bval, t1 = s1 + bval;

    float mn0 = t0, mx0 = t0, mn1 = t1, mx1 = t1;
#pragma unroll
    for (int off = 32; off > 0; off >>= 1) {
        mn0 = fminf(mn0, __shfl_xor(mn0, off));
        mx0 = fmaxf(mx0, __shfl_xor(mx0, off));
        mn1 = fminf(mn1, __shfl_xor(mn1, off));
        mx1 = fmaxf(mx1, __shfl_xor(mx1, off));
    }
    const int wv = t >> 6;
    if ((t & 63) == 0) {
        red[wv][0] = mn0; red[wv][1] = mx0;
        red[wv][2] = mn1; red[wv][3] = mx1;
    }
    __syncthreads();
    if ((t & 63) == 0 && (wv & 1) == 0) {   // waves 0,2 finalize px pair pp
        const int pw = wv ^ 1;
        const float amn0 = fminf(mn0, red[pw][0]);
        const float amx0 = fmaxf(mx0, red[pw][1]);
        const float amn1 = fminf(mn1, red[pw][2]);
        const float amx1 = fmaxf(mx1, red[pw][3]);
        {
            const float sv = (amx0 - amn0) / QMAX_;
            float z = -amn0 / sv;
            z = fmaxf(z, 0.f);      // fmaxf(NaN,0)=0 matches where(isnan,0)
            z = fminf(z, QMAX_);
            z = truncf(z);
            spar[pp][0][0] = sv; spar[pp][0][1] = z; spar[pp][0][2] = 1.0f / sv;
        }
        {
            const float sv = (amx1 - amn1) / QMAX_;
            float z = -amn1 / sv;
            z = fmaxf(z, 0.f);
            z = fminf(z, QMAX_);
            z = truncf(z);
            spar[pp][1][0] = sv; spar[pp][1][1] = z; spar[pp][1][2] = 1.0f / sv;
        }
    }
    __syncthreads();

    // ================= fake-quant accumulate (register-held partials) =======
    const float sc0 = spar[pp][0][0], zp0 = spar[pp][0][1], iv0 = spar[pp][0][2];
    const float sc1 = spar[pp][1][0], zp1 = spar[pp][1][1], iv1 = spar[pp][1][2];
    float q0 = 0.f, q1 = 0.f;
#pragma unroll
    for (int j = 0; j < NCH; ++j) {
        float qn0 = rintf(v0[j] * iv0) + zp0;   // rintf == round-half-even
        qn0 = fminf(fmaxf(qn0, 0.f), QMAX_);
        q0 += (qn0 - zp0) * sc0;
        float qn1 = rintf(v1[j] * iv1) + zp1;
        qn1 = fminf(fmaxf(qn1, 0.f), QMAX_);
        q1 += (qn1 - zp1) * sc1;
    }
    qb[2 * pp + 0][oc] = q0;
    qb[2 * pp + 1][oc] = q1;
    __syncthreads();

    if (t < 128)
        *(float4*)(out + (size_t)t * L_ + l0) =
            make_float4(qb[0][t], qb[1][t], qb[2][t], qb[3][t]);
}

extern "C" void kernel_launch(void* const* d_in, const int* in_sizes, int n_in,
                              void* d_out, int out_size, void* d_ws, size_t ws_size,
                              hipStream_t stream) {
    const float* x    = (const float*)d_in[0];  // 128*32*32
    const float* w    = (const float*)d_in[1];  // 128*1152
    const float* bias = (const float*)d_in[2];  // 128
    float* out = (float*)d_out;                 // 128*1024
    (void)d_ws; (void)ws_size;                  // zero-workspace path

    fused_cas<<<256, 256, 0, stream>>>(x, w, bias, out);
}

// Round 3
// 500.866 us; speedup vs baseline: 1.1070x; 1.1070x over previous
//
#include <hip/hip_runtime.h>

// casConv2d: B=1, C=128, H=W=32, OC=128, K=3, pad=1, stride=1.
// L = 1024, CKK = 1152 = 36 exact 32-tap chunks (reference front-pad chunk == 0).
//
// Round-11. R2 post-mortem: fused kernel spilled catastrophically
// (VGPR=256 cap, 1.1 GB HBM traffic/dispatch = scratch, VALUBusy 1%).
// Cause: fully-unrolled 36-iter loop + issue-early REGISTER staging (17
// regs/iter) -> software pipelining hoisted several iterations of staging
// loads on top of the 72-reg v0/v1 arrays -> spill. R2 also proved the big
// structural fact: with zero workspace the harness skips the 43us 256MiB
// ws-poison fill, and fixed overhead is ~22us (554 = 532 + 22).
//
// R3 = R2 with ONE change: W staging via __builtin_amdgcn_global_load_lds
// (async global->LDS, no dest registers -> nothing to hoist, per-iter
// transient state ~3 regs). LDS stays linear for the DMA (wave-uniform base
// + lane*16); the XOR bank-swizzle is preserved by inverse-permuting the
// per-lane GLOBAL source address (m173 pattern). x slice (512B) stays
// reg-staged (needs zero-fill predication). Numerics & epilogue identical
// to R2 (which PASSED, absmax 0.03515625).
#define L_    1024
#define CKK_  1152
#define QMAX_ 255.0f
#define NCH   36

typedef __attribute__((address_space(3))) void       lds_void;
typedef const __attribute__((address_space(1))) void gm_void;

static __device__ __forceinline__ void gload16(const float* gp, float* lp) {
    // size must be a literal 16 (global_load_lds_dwordx4)
    __builtin_amdgcn_global_load_lds((gm_void*)gp, (lds_void*)lp, 16, 0, 0);
}

__global__ __launch_bounds__(256) void fused_cas(
    const float* __restrict__ x,      // [128][32][32]
    const float* __restrict__ w,      // [128][1152]
    const float* __restrict__ bias,   // [128]
    float* __restrict__ out)          // [128][1024]
{
    // W buffer: swizzled [oc][tap] rows of 32 floats (128B). Compute reads
    // float4 at oc*32 + 4*(k16 ^ (oc&7)) -> per-16B-slot 8 lanes = the
    // structural wave64-b128 minimum (8cy), no extra conflicts.
    __shared__ __align__(16) float Wb[2][128 * 32];   // 2 x 16KB
    __shared__ __align__(16) float xs[2][32 * 4];     // [tap][px-local], 2 x 512B
    __shared__ float red[4][4];                       // per-wave {mn0,mx0,mn1,mx1}
    __shared__ float spar[2][2][3];                   // [pp][s]{sc,zp,iv}
    __shared__ float qb[4][128];                      // [px-local][oc]

    const int t   = threadIdx.x;
    const int b   = blockIdx.x;
    const int oc  = t & 127;
    const int pp  = t >> 7;            // waves 0,1 -> px {0,1}; waves 2,3 -> {2,3}
    const int ocm = oc & 7;
    const int oh  = b >> 3;            // all 4 px share one output row
    const int ow0 = (b & 7) * 4;
    const int l0  = b * 4;

    // ---- W staging via global_load_lds: 4 calls/thread/chunk ----
    // call it: 16B slot s = it*256 + t ; oc_s = s>>3 ; q = s&7 (physical quad)
    // LDS float base (wave-uniform): it*1024 + (t>>6)*256 ; HW adds lane*16B.
    // slot contents must be W[oc_s][j*32 + 4*(q ^ (oc_s&7))] (inverse swizzle).
    int wgo[4];                        // global float offset sans j*32
#pragma unroll
    for (int it = 0; it < 4; ++it) {
        const int s  = it * 256 + t;
        const int os = s >> 3, q = s & 7;
        wgo[it] = os * CKK_ + 4 * (q ^ (os & 7));
    }
    const int wlb = (t >> 6) * 256;    // wave-uniform float offset within it-block

    // ---- x staging: one predicated scalar per thread (t<128) per chunk ----
    // layout xs[tap][px]: lds idx = (t>>2)*4 + (t&3) == t
    const int xtap = t >> 2, xll = t & 3;

    float v0[NCH], v1[NCH];            // per-chunk partials, statically indexed

    // ================= prologue: stage chunk 0 =================
    {
#pragma unroll
        for (int it = 0; it < 4; ++it)
            gload16(w + wgo[it], &Wb[0][it * 1024 + wlb]);
        if (t < 128) {
            const int d  = xtap;                       // chunk 0
            const int c  = d / 9, r = d - 9 * c;
            const int kh = r / 3, kw = r - 3 * kh;
            const int iy = oh + kh - 1, ix = ow0 + xll + kw - 1;
            const bool ok = ((unsigned)iy < 32u) & ((unsigned)ix < 32u);
            const float vv = x[ok ? (c * 1024 + iy * 32 + ix) : 0];
            xs[0][t] = ok ? vv : 0.f;
        }
        __syncthreads();               // compiler drains vmcnt before barrier
    }

    // ================= main chunk loop (fully unrolled) =================
#pragma unroll
    for (int j = 0; j < NCH; ++j) {
        const int cur = j & 1, nxt = cur ^ 1;

        // issue-early for chunk j+1: x global load first (so its ds_write
        // later only waits on it), then the 4 async W DMAs.
        float xr = 0.f;
        if (j + 1 < NCH) {
            if (t < 128) {
                const int d  = (j + 1) * 32 + xtap;
                const int c  = d / 9, r = d - 9 * c;
                const int kh = r / 3, kw = r - 3 * kh;
                const int iy = oh + kh - 1, ix = ow0 + xll + kw - 1;
                const bool ok = ((unsigned)iy < 32u) & ((unsigned)ix < 32u);
                const float vv = x[ok ? (c * 1024 + iy * 32 + ix) : 0];
                xr = ok ? vv : 0.f;
            }
#pragma unroll
            for (int it = 0; it < 4; ++it)
                gload16(w + wgo[it] + (j + 1) * 32, &Wb[nxt][it * 1024 + wlb]);
        }

        // compute chunk j: 32-tap ascending FMA chain per (oc, px)
        float a0 = 0.f, a1 = 0.f;
        const float* Wp = &Wb[cur][oc * 32];
        const float* Xp = &xs[cur][2 * pp];
#pragma unroll
        for (int k16 = 0; k16 < 8; ++k16) {
            const float4 wv  = *(const float4*)(Wp + 4 * (k16 ^ ocm));
            const float2 xv0 = *(const float2*)(Xp + (k16 * 4 + 0) * 4);
            const float2 xv1 = *(const float2*)(Xp + (k16 * 4 + 1) * 4);
            const float2 xv2 = *(const float2*)(Xp + (k16 * 4 + 2) * 4);
            const float2 xv3 = *(const float2*)(Xp + (k16 * 4 + 3) * 4);
            a0 = fmaf(wv.x, xv0.x, a0); a1 = fmaf(wv.x, xv0.y, a1);
            a0 = fmaf(wv.y, xv1.x, a0); a1 = fmaf(wv.y, xv1.y, a1);
            a0 = fmaf(wv.z, xv2.x, a0); a1 = fmaf(wv.z, xv2.y, a1);
            a0 = fmaf(wv.w, xv3.x, a0); a1 = fmaf(wv.w, xv3.y, a1);
        }
        v0[j] = a0; v1[j] = a1;

        if (j + 1 < NCH && t < 128) xs[nxt][t] = xr;
        __syncthreads();
    }

    // ================= totals + per-px minmax =================
    float s0 = 0.f, s1 = 0.f;
#pragma unroll
    for (int j = 0; j < NCH; ++j) { s0 += v0[j]; s1 += v1[j]; }
    const float bval = bias[oc];
    const float t0 = s0 + bval, t1 = s1 + bval;

    float mn0 = t0, mx0 = t0, mn1 = t1, mx1 = t1;
#pragma unroll
    for (int off = 32; off > 0; off >>= 1) {
        mn0 = fminf(mn0, __shfl_xor(mn0, off));
        mx0 = fmaxf(mx0, __shfl_xor(mx0, off));
        mn1 = fminf(mn1, __shfl_xor(mn1, off));
        mx1 = fmaxf(mx1, __shfl_xor(mx1, off));
    }
    const int wv = t >> 6;
    if ((t & 63) == 0) {
        red[wv][0] = mn0; red[wv][1] = mx0;
        red[wv][2] = mn1; red[wv][3] = mx1;
    }
    __syncthreads();
    if ((t & 63) == 0 && (wv & 1) == 0) {   // waves 0,2 finalize px pair pp
        const int pw = wv ^ 1;
        const float amn0 = fminf(mn0, red[pw][0]);
        const float amx0 = fmaxf(mx0, red[pw][1]);
        const float amn1 = fminf(mn1, red[pw][2]);
        const float amx1 = fmaxf(mx1, red[pw][3]);
        {
            const float sv = (amx0 - amn0) / QMAX_;
            float z = -amn0 / sv;
            z = fmaxf(z, 0.f);      // fmaxf(NaN,0)=0 matches where(isnan,0)
            z = fminf(z, QMAX_);
            z = truncf(z);
            spar[pp][0][0] = sv; spar[pp][0][1] = z; spar[pp][0][2] = 1.0f / sv;
        }
        {
            const float sv = (amx1 - amn1) / QMAX_;
            float z = -amn1 / sv;
            z = fmaxf(z, 0.f);
            z = fminf(z, QMAX_);
            z = truncf(z);
            spar[pp][1][0] = sv; spar[pp][1][1] = z; spar[pp][1][2] = 1.0f / sv;
        }
    }
    __syncthreads();

    // ================= fake-quant accumulate (register-held partials) =======
    const float sc0 = spar[pp][0][0], zp0 = spar[pp][0][1], iv0 = spar[pp][0][2];
    const float sc1 = spar[pp][1][0], zp1 = spar[pp][1][1], iv1 = spar[pp][1][2];
    float q0 = 0.f, q1 = 0.f;
#pragma unroll
    for (int j = 0; j < NCH; ++j) {
        float qn0 = rintf(v0[j] * iv0) + zp0;   // rintf == round-half-even
        qn0 = fminf(fmaxf(qn0, 0.f), QMAX_);
        q0 += (qn0 - zp0) * sc0;
        float qn1 = rintf(v1[j] * iv1) + zp1;
        qn1 = fminf(fmaxf(qn1, 0.f), QMAX_);
        q1 += (qn1 - zp1) * sc1;
    }
    qb[2 * pp + 0][oc] = q0;
    qb[2 * pp + 1][oc] = q1;
    __syncthreads();

    if (t < 128)
        *(float4*)(out + (size_t)t * L_ + l0) =
            make_float4(qb[0][t], qb[1][t], qb[2][t], qb[3][t]);
}

extern "C" void kernel_launch(void* const* d_in, const int* in_sizes, int n_in,
                              void* d_out, int out_size, void* d_ws, size_t ws_size,
                              hipStream_t stream) {
    const float* x    = (const float*)d_in[0];  // 128*32*32
    const float* w    = (const float*)d_in[1];  // 128*1152
    const float* bias = (const float*)d_in[2];  // 128
    float* out = (float*)d_out;                 // 128*1024
    (void)d_ws; (void)ws_size;                  // zero-workspace: harness skips
                                                // the 256MiB ws poison fill

    fused_cas<<<256, 256, 0, stream>>>(x, w, bias, out);
}

// Round 4
// 102.293 us; speedup vs baseline: 5.4203x; 4.8964x over previous
//
#include <hip/hip_runtime.h>

// casConv2d: B=1, C=128, H=W=32, OC=128, K=3, pad=1, stride=1.
// L = 1024, CKK = 1152 = 36 exact 32-tap chunks (reference front-pad chunk == 0).
//
// Round-12. R2/R3 post-mortem: BOTH register-partial variants spilled
// identically (VGPR=256, ~1.1GB scratch traffic/dispatch, ~457us) -- removing
// staging dest-regs (R3, global_load_lds) changed nothing, so the spill
// driver is the fully-unrolled 36-iter loop + 72-reg v0/v1 arrays letting the
// scheduler build huge live ranges. Also corrected: the 256MiB ws-poison fill
// is UNCONDITIONAL (~44us gap in both R2 and R3), so floor = ~45us + kernel.
//
// R4: per-chunk partials go to LDS (vbuf[36][256] float2, 72KB, 2-way bank
// alias = free), running sums stay in 2 regs, chunk loop stays ROLLED (no
// register arrays at all -> nothing to spill, ~40 VGPR). W staging keeps the
// R3-verified global_load_lds + pre-swizzled-source path (16KB/chunk, double
// buffered). x layout flips to [px][tap]: compute = 8 b128 W reads (swizzled,
// conflict-free) + 16 b128 x broadcasts per thread-chunk. LDS ~108KB/block,
// 1 block/CU. Numerics bit-identical to the PASSING R2/R3 path: same 32-tap
// ascending FMA chains, same j-ascending totals, same quant ops.
#define L_    1024
#define CKK_  1152
#define QMAX_ 255.0f
#define NCH   36

typedef __attribute__((address_space(3))) void       lds_void;
typedef const __attribute__((address_space(1))) void gm_void;

static __device__ __forceinline__ void gload16(const float* gp, float* lp) {
    // size must be a literal 16 (emits global_load_lds_dwordx4)
    __builtin_amdgcn_global_load_lds((gm_void*)gp, (lds_void*)lp, 16, 0, 0);
}

// x fetch for chunk jj, tap, pixel px of this block (predicated zero-fill)
static __device__ __forceinline__ float xfetch(const float* __restrict__ x,
                                               int jj, int tap, int oh,
                                               int ow0, int px) {
    const int d  = jj * 32 + tap;
    const int c  = d / 9, r = d - 9 * c;
    const int kh = r / 3, kw = r - 3 * kh;
    const int iy = oh + kh - 1, ix = ow0 + px + kw - 1;
    const bool ok = ((unsigned)iy < 32u) & ((unsigned)ix < 32u);
    const float vv = x[ok ? (c * 1024 + iy * 32 + ix) : 0];
    return ok ? vv : 0.f;
}

__global__ __launch_bounds__(256) void fused_cas(
    const float* __restrict__ x,      // [128][32][32]
    const float* __restrict__ w,      // [128][1152]
    const float* __restrict__ bias,   // [128]
    float* __restrict__ out)          // [128][1024]
{
    // W: swizzled [oc][tap-quad] rows (128B). Compute reads float4 at
    // oc*32 + 4*(k16 ^ (oc&7)): per 8-oc octet the 8 lanes cover all 32
    // banks -> structural wave64-b128 minimum, no extra conflicts.
    __shared__ __align__(16) float  Wb[2][128 * 32];  // 32 KB
    __shared__ __align__(16) float  xs[2][4 * 32];    // [px][tap], 1 KB
    __shared__ __align__(16) float2 vbuf[NCH][256];   // 72 KB per-thread chunk partials
    __shared__ float red[4][4];                       // per-wave {mn0,mx0,mn1,mx1}
    __shared__ float spar[2][2][3];                   // [pp][s]{sc,zp,iv}
    __shared__ float qb[4][128];                      // [px-local][oc]

    const int t   = threadIdx.x;
    const int b   = blockIdx.x;
    const int oc  = t & 127;
    const int pp  = t >> 7;            // waves 0,1 -> px {0,1}; waves 2,3 -> {2,3}
    const int ocm = oc & 7;
    const int oh  = b >> 3;            // all 4 px share one output row
    const int ow0 = (b & 7) * 4;
    const int l0  = b * 4;

    // W staging: slot s = it*256 + t ; row os = s>>3 ; physical quad q = s&7.
    // Slot q of row os must hold logical quad (q ^ (os&7)) -> pre-swizzled
    // global source; LDS dest is linear (wave-uniform base + lane*16).
    int wgo[4];
#pragma unroll
    for (int it = 0; it < 4; ++it) {
        const int s  = it * 256 + t;
        const int os = s >> 3, q = s & 7;
        wgo[it] = os * CKK_ + 4 * (q ^ (os & 7));
    }
    const int wlb = (t >> 6) * 256;    // wave-uniform float offset per it-block

    // ---- prologue: stage chunk 0 ----
#pragma unroll
    for (int it = 0; it < 4; ++it)
        gload16(w + wgo[it], &Wb[0][it * 1024 + wlb]);
    if (t < 128) xs[0][t] = xfetch(x, 0, t & 31, oh, ow0, t >> 5);
    __syncthreads();                   // compiler drains vmcnt before barrier

    // ---- main chunk loop (ROLLED: no register arrays, nothing to spill) ----
    float s0 = 0.f, s1 = 0.f;
    for (int j = 0; j < NCH; ++j) {
        const int  cur  = j & 1, nxt = cur ^ 1;
        const bool more = (j + 1 < NCH);

        // issue-early staging for chunk j+1
        float xr = 0.f;
        if (more) {
            if (t < 128) xr = xfetch(x, j + 1, t & 31, oh, ow0, t >> 5);
#pragma unroll
            for (int it = 0; it < 4; ++it)
                gload16(w + wgo[it] + (j + 1) * 32, &Wb[nxt][it * 1024 + wlb]);
        }

        // compute chunk j: 32-tap ascending FMA chain per (oc, px)
        float a0 = 0.f, a1 = 0.f;
        const float* Wp = &Wb[cur][oc * 32];
        const float* X0 = &xs[cur][(2 * pp) * 32];
        const float* X1 = &xs[cur][(2 * pp + 1) * 32];
#pragma unroll
        for (int k16 = 0; k16 < 8; ++k16) {
            const float4 wv = *(const float4*)(Wp + 4 * (k16 ^ ocm));
            const float4 xa = *(const float4*)(X0 + 4 * k16);
            const float4 xb = *(const float4*)(X1 + 4 * k16);
            a0 = fmaf(wv.x, xa.x, a0); a1 = fmaf(wv.x, xb.x, a1);
            a0 = fmaf(wv.y, xa.y, a0); a1 = fmaf(wv.y, xb.y, a1);
            a0 = fmaf(wv.z, xa.z, a0); a1 = fmaf(wv.z, xb.z, a1);
            a0 = fmaf(wv.w, xa.w, a0); a1 = fmaf(wv.w, xb.w, a1);
        }
        vbuf[j][t] = make_float2(a0, a1);  // thread-private slot, no barrier dep
        s0 += a0; s1 += a1;

        if (more && t < 128) xs[nxt][t] = xr;
        __syncthreads();
    }

    // ---- totals + per-px minmax (identical to passing R2/R3 epilogue) ----
    const float bval = bias[oc];
    const float t0 = s0 + bval, t1 = s1 + bval;

    float mn0 = t0, mx0 = t0, mn1 = t1, mx1 = t1;
#pragma unroll
    for (int off = 32; off > 0; off >>= 1) {
        mn0 = fminf(mn0, __shfl_xor(mn0, off));
        mx0 = fmaxf(mx0, __shfl_xor(mx0, off));
        mn1 = fminf(mn1, __shfl_xor(mn1, off));
        mx1 = fmaxf(mx1, __shfl_xor(mx1, off));
    }
    const int wv = t >> 6;
    if ((t & 63) == 0) {
        red[wv][0] = mn0; red[wv][1] = mx0;
        red[wv][2] = mn1; red[wv][3] = mx1;
    }
    __syncthreads();
    if ((t & 63) == 0 && (wv & 1) == 0) {   // waves 0,2 finalize px pair pp
        const int pw = wv ^ 1;
        const float amn0 = fminf(mn0, red[pw][0]);
        const float amx0 = fmaxf(mx0, red[pw][1]);
        const float amn1 = fminf(mn1, red[pw][2]);
        const float amx1 = fmaxf(mx1, red[pw][3]);
        {
            const float sv = (amx0 - amn0) / QMAX_;
            float z = -amn0 / sv;
            z = fmaxf(z, 0.f);      // fmaxf(NaN,0)=0 matches where(isnan,0)
            z = fminf(z, QMAX_);
            z = truncf(z);
            spar[pp][0][0] = sv; spar[pp][0][1] = z; spar[pp][0][2] = 1.0f / sv;
        }
        {
            const float sv = (amx1 - amn1) / QMAX_;
            float z = -amn1 / sv;
            z = fmaxf(z, 0.f);
            z = fminf(z, QMAX_);
            z = truncf(z);
            spar[pp][1][0] = sv; spar[pp][1][1] = z; spar[pp][1][2] = 1.0f / sv;
        }
    }
    __syncthreads();

    // ---- fake-quant accumulate over LDS-held partials (j ascending) ----
    const float sc0 = spar[pp][0][0], zp0 = spar[pp][0][1], iv0 = spar[pp][0][2];
    const float sc1 = spar[pp][1][0], zp1 = spar[pp][1][1], iv1 = spar[pp][1][2];
    float q0 = 0.f, q1 = 0.f;
    for (int j = 0; j < NCH; ++j) {
        const float2 vvp = vbuf[j][t];
        float qn0 = rintf(vvp.x * iv0) + zp0;   // rintf == round-half-even
        qn0 = fminf(fmaxf(qn0, 0.f), QMAX_);
        q0 += (qn0 - zp0) * sc0;
        float qn1 = rintf(vvp.y * iv1) + zp1;
        qn1 = fminf(fmaxf(qn1, 0.f), QMAX_);
        q1 += (qn1 - zp1) * sc1;
    }
    qb[2 * pp + 0][oc] = q0;
    qb[2 * pp + 1][oc] = q1;
    __syncthreads();

    if (t < 128)
        *(float4*)(out + (size_t)t * L_ + l0) =
            make_float4(qb[0][t], qb[1][t], qb[2][t], qb[3][t]);
}

extern "C" void kernel_launch(void* const* d_in, const int* in_sizes, int n_in,
                              void* d_out, int out_size, void* d_ws, size_t ws_size,
                              hipStream_t stream) {
    const float* x    = (const float*)d_in[0];  // 128*32*32
    const float* w    = (const float*)d_in[1];  // 128*1152
    const float* bias = (const float*)d_in[2];  // 128
    float* out = (float*)d_out;                 // 128*1024
    (void)d_ws; (void)ws_size;                  // zero-workspace

    fused_cas<<<256, 256, 0, stream>>>(x, w, bias, out);
}

// Round 5
// 92.625 us; speedup vs baseline: 5.9860x; 1.1044x over previous
//
#include <hip/hip_runtime.h>

// casConv2d: B=1, C=128, H=W=32, OC=128, K=3, pad=1, stride=1.
// L = 1024, CKK = 1152 = 36 exact 32-tap chunks (reference front-pad chunk == 0).
//
// Round-13. R4 post-mortem: spill fixed (VGPR 132, scratch gone) but kernel
// stuck at 62us: 1 wave/SIMD (occupancy 10%), VALUBusy 11%, and a
// barrier+vmcnt(0) drain EVERY chunk -> ~4100 cyc/chunk of exposed LDS/L2
// latency vs ~200 of issue work. FMA floor at this occupancy is ~1.9us.
// Also confirmed: the 256MiB ws-poison fill (~41-46us) is UNCONDITIONAL,
// so total = fill + kernel; target kernel <10us.
//
// R5: delete the synchronization. W is L2/L1-resident (576KB/XCD; 16KB/chunk
// per CU, shared by the two waves reading the same oc half), so W skips LDS
// entirely: each thread reads its own W[oc] row as 8 dwordx4 per chunk,
// manually double-buffered in registers (ping-pong wc/wn, rolled j+=2 loop ->
// bounded live ranges, no R2-style unroll hoisting). x for ALL 36 chunks
// (18KB) staged to LDS once in the prologue. Main loop has ZERO barriers:
// next-chunk W loads overlap current-chunk FMAs via counted vmcnt; x reads
// are LDS broadcasts (conflict-free). vbuf per-chunk partials (72KB LDS) and
// the R4-verified epilogue are unchanged -> bit-identical numerics
// (absmax 0.03515625 expected).
#define L_    1024
#define CKK_  1152
#define QMAX_ 255.0f
#define NCH   36

__global__ __launch_bounds__(256) void fused_cas(
    const float* __restrict__ x,      // [128][32][32]
    const float* __restrict__ w,      // [128][1152]
    const float* __restrict__ bias,   // [128]
    float* __restrict__ out)          // [128][1024]
{
    __shared__ __align__(16) float  xs[NCH * 32 * 4];   // [j][tap][px], 18 KB
    __shared__ __align__(16) float2 vbuf[NCH][256];     // per-thread chunk partials, 72 KB
    __shared__ float red[4][4];                         // per-wave {mn0,mx0,mn1,mx1}
    __shared__ float spar[2][2][3];                     // [pp][s]{sc,zp,iv}
    __shared__ float qb[4][128];                        // [px-local][oc]

    const int t   = threadIdx.x;
    const int b   = blockIdx.x;
    const int oc  = t & 127;
    const int pp  = t >> 7;            // waves 0,1 -> px {0,1}; waves 2,3 -> {2,3}
    const int oh  = b >> 3;            // all 4 px share one output row
    const int ow0 = (b & 7) * 4;
    const int l0  = b * 4;

    // ---- prologue: stage ALL x for this block (4608 elems = 18/thread) ----
    for (int i = 0; i < 18; ++i) {
        const int e   = i * 256 + t;
        const int j   = e >> 7;            // chunk
        const int tap = (e >> 2) & 31;
        const int px  = e & 3;
        const int d   = j * 32 + tap;
        const int c   = d / 9, r = d - 9 * c;
        const int kh  = r / 3, kw = r - 3 * kh;
        const int iy  = oh + kh - 1, ix = ow0 + px + kw - 1;
        const bool ok = ((unsigned)iy < 32u) & ((unsigned)ix < 32u);
        const float vv = x[ok ? (c * 1024 + iy * 32 + ix) : 0];
        xs[e] = ok ? vv : 0.f;
    }
    __syncthreads();

    // ---- main loop: no barriers, W direct from global (L1/L2-resident) ----
    const float4* wrow = (const float4*)(w + oc * CKK_);   // 8 float4 per chunk
    const float*  xp   = xs + 2 * pp;                      // px pair base

    float s0 = 0.f, s1 = 0.f;

    auto chunk = [&](int j, const float4* wreg) {
        float a0 = 0.f, a1 = 0.f;
        const float* xj = xp + j * 128;    // [tap][px] floats for this chunk
#pragma unroll
        for (int k4 = 0; k4 < 8; ++k4) {
            const float4 wv = wreg[k4];
            const float2 x0 = *(const float2*)(xj + (4 * k4 + 0) * 4);
            const float2 x1 = *(const float2*)(xj + (4 * k4 + 1) * 4);
            const float2 x2 = *(const float2*)(xj + (4 * k4 + 2) * 4);
            const float2 x3 = *(const float2*)(xj + (4 * k4 + 3) * 4);
            a0 = fmaf(wv.x, x0.x, a0); a1 = fmaf(wv.x, x0.y, a1);
            a0 = fmaf(wv.y, x1.x, a0); a1 = fmaf(wv.y, x1.y, a1);
            a0 = fmaf(wv.z, x2.x, a0); a1 = fmaf(wv.z, x2.y, a1);
            a0 = fmaf(wv.w, x3.x, a0); a1 = fmaf(wv.w, x3.y, a1);
        }
        vbuf[j][t] = make_float2(a0, a1);  // thread-private slot, no sync needed
        s0 += a0; s1 += a1;
    };

    float4 wc[8], wn[8];
#pragma unroll
    for (int k4 = 0; k4 < 8; ++k4) wc[k4] = wrow[k4];      // chunk 0

    for (int j = 0; j < NCH; j += 2) {
        // prefetch chunk j+1 while computing chunk j
#pragma unroll
        for (int k4 = 0; k4 < 8; ++k4) wn[k4] = wrow[(j + 1) * 8 + k4];
        chunk(j, wc);
        // prefetch chunk j+2 while computing chunk j+1
        if (j + 2 < NCH) {
#pragma unroll
            for (int k4 = 0; k4 < 8; ++k4) wc[k4] = wrow[(j + 2) * 8 + k4];
        }
        chunk(j + 1, wn);
    }

    // ---- totals + per-px minmax (identical to passing R4 epilogue) ----
    const float bval = bias[oc];
    const float t0 = s0 + bval, t1 = s1 + bval;

    float mn0 = t0, mx0 = t0, mn1 = t1, mx1 = t1;
#pragma unroll
    for (int off = 32; off > 0; off >>= 1) {
        mn0 = fminf(mn0, __shfl_xor(mn0, off));
        mx0 = fmaxf(mx0, __shfl_xor(mx0, off));
        mn1 = fminf(mn1, __shfl_xor(mn1, off));
        mx1 = fmaxf(mx1, __shfl_xor(mx1, off));
    }
    const int wv = t >> 6;
    if ((t & 63) == 0) {
        red[wv][0] = mn0; red[wv][1] = mx0;
        red[wv][2] = mn1; red[wv][3] = mx1;
    }
    __syncthreads();
    if ((t & 63) == 0 && (wv & 1) == 0) {   // waves 0,2 finalize px pair pp
        const int pw = wv ^ 1;
        const float amn0 = fminf(mn0, red[pw][0]);
        const float amx0 = fmaxf(mx0, red[pw][1]);
        const float amn1 = fminf(mn1, red[pw][2]);
        const float amx1 = fmaxf(mx1, red[pw][3]);
        {
            const float sv = (amx0 - amn0) / QMAX_;
            float z = -amn0 / sv;
            z = fmaxf(z, 0.f);      // fmaxf(NaN,0)=0 matches where(isnan,0)
            z = fminf(z, QMAX_);
            z = truncf(z);
            spar[pp][0][0] = sv; spar[pp][0][1] = z; spar[pp][0][2] = 1.0f / sv;
        }
        {
            const float sv = (amx1 - amn1) / QMAX_;
            float z = -amn1 / sv;
            z = fmaxf(z, 0.f);
            z = fminf(z, QMAX_);
            z = truncf(z);
            spar[pp][1][0] = sv; spar[pp][1][1] = z; spar[pp][1][2] = 1.0f / sv;
        }
    }
    __syncthreads();

    // ---- fake-quant accumulate over LDS-held partials (j ascending) ----
    const float sc0 = spar[pp][0][0], zp0 = spar[pp][0][1], iv0 = spar[pp][0][2];
    const float sc1 = spar[pp][1][0], zp1 = spar[pp][1][1], iv1 = spar[pp][1][2];
    float q0 = 0.f, q1 = 0.f;
    for (int j = 0; j < NCH; ++j) {
        const float2 vvp = vbuf[j][t];
        float qn0 = rintf(vvp.x * iv0) + zp0;   // rintf == round-half-even
        qn0 = fminf(fmaxf(qn0, 0.f), QMAX_);
        q0 += (qn0 - zp0) * sc0;
        float qn1 = rintf(vvp.y * iv1) + zp1;
        qn1 = fminf(fmaxf(qn1, 0.f), QMAX_);
        q1 += (qn1 - zp1) * sc1;
    }
    qb[2 * pp + 0][oc] = q0;
    qb[2 * pp + 1][oc] = q1;
    __syncthreads();

    if (t < 128)
        *(float4*)(out + (size_t)t * L_ + l0) =
            make_float4(qb[0][t], qb[1][t], qb[2][t], qb[3][t]);
}

extern "C" void kernel_launch(void* const* d_in, const int* in_sizes, int n_in,
                              void* d_out, int out_size, void* d_ws, size_t ws_size,
                              hipStream_t stream) {
    const float* x    = (const float*)d_in[0];  // 128*32*32
    const float* w    = (const float*)d_in[1];  // 128*1152
    const float* bias = (const float*)d_in[2];  // 128
    float* out = (float*)d_out;                 // 128*1024
    (void)d_ws; (void)ws_size;                  // ws unused (fill is unconditional)

    fused_cas<<<256, 256, 0, stream>>>(x, w, bias, out);
}

// Round 6
// 75.509 us; speedup vs baseline: 7.3429x; 1.2267x over previous
//
#include <hip/hip_runtime.h>

// casConv2d: B=1, C=128, H=W=32, OC=128, K=3, pad=1, stride=1.
// L = 1024, CKK = 1152 = 36 exact 32-tap chunks (reference front-pad chunk == 0).
//
// Round-14. R5 post-mortem: barriers gone, spill gone, but kernel stuck at
// 40.6us with VALUBusy 12%. Diagnosis (arithmetic matches counters): W reg
// loads are 64 lanes x 16B at 4.6KB stride -> 64 lines per dwordx4; per chunk
// per CU 4 waves x 8 loads x 64 lines = 2048 line-requests (waves 0/2, 1/3
// read IDENTICAL data) ~= 2100 cyc/chunk at ~1 line/cyc L1 service; measured
// 2670 cyc/chunk. Kernel is L1-line-service bound on scattered duplicated W.
//
// R6: (1) pre-transpose W into d_ws as wt4[tapquad 288][oc 128] float4 (576KB;
// the 256MiB ws poison fill is UNCONDITIONAL so ws use is free) -> a wave's
// 8 per-chunk loads become 1KB contiguous (16 lines/instr, 4x less);
// (2) kill duplication: wave-pair 0 (oc0-127) computes chunks 0..17 for ALL
// 4 px, wave-pair 1 chunks 18..35 -> W read once per CU per chunk (16KB) and
// amortized over 4 outputs/thread. Partials vbuf[j][oc] float4 (72KB LDS,
// thread-private slots, contiguous b128). Epilogue RECOMPUTES totals from
// vbuf in ascending-j order = exact R5 summation order, then runs the
// R5-verified minmax/quant/store code verbatim (px-pair select is
// wave-uniform). Numerics bit-identical -> absmax 0.03515625 expected.
#define L_    1024
#define CKK_  1152
#define QMAX_ 255.0f
#define NCH   36

// ---- W transpose: w[oc][1152] -> wt4[tq][oc] (tq = tap quad, 288x128 f4) ----
__global__ __launch_bounds__(256) void wtrans(
    const float* __restrict__ w, float* __restrict__ wt)
{
    const int e  = blockIdx.x * 256 + threadIdx.x;   // 36864 float4 slots
    const int oc = e / 288, tq = e - 288 * oc;
    const float4 v = ((const float4*)(w + oc * CKK_))[tq];   // coalesced read
    ((float4*)wt)[tq * 128 + oc] = v;                        // scattered write (L2)
}

template <bool WT>
__global__ __launch_bounds__(256) void fused_cas(
    const float* __restrict__ x,      // [128][32][32]
    const float* __restrict__ w,      // [128][1152]        (WT=false path)
    const float4* __restrict__ wt4,   // [288][128] float4  (WT=true path)
    const float* __restrict__ bias,   // [128]
    float* __restrict__ out)          // [128][1024]
{
    __shared__ __align__(16) float  xs[NCH * 32 * 4];   // [j][tap][px], 18 KB
    __shared__ __align__(16) float4 vbuf[NCH][128];     // [j][oc] px0..3, 72 KB
    __shared__ float red[4][4];                         // per-wave {mn0,mx0,mn1,mx1}
    __shared__ float spar[2][2][3];                     // [pp][s]{sc,zp,iv}
    __shared__ float qb[4][128];                        // [px-local][oc]

    const int t   = threadIdx.x;
    const int b   = blockIdx.x;
    const int oc  = t & 127;
    const int wp  = t >> 7;            // chunk-ownership wave-pair (main loop)
    const int pp  = t >> 7;            // px-pair (epilogue, same split as R5)
    const int oh  = b >> 3;            // all 4 px share one output row
    const int ow0 = (b & 7) * 4;
    const int l0  = b * 4;

    // ---- prologue: stage ALL x for this block (4608 elems = 18/thread) ----
    for (int i = 0; i < 18; ++i) {
        const int e   = i * 256 + t;
        const int j   = e >> 7;            // chunk
        const int tap = (e >> 2) & 31;
        const int px  = e & 3;
        const int d   = j * 32 + tap;
        const int c   = d / 9, r = d - 9 * c;
        const int kh  = r / 3, kw = r - 3 * kh;
        const int iy  = oh + kh - 1, ix = ow0 + px + kw - 1;
        const bool ok = ((unsigned)iy < 32u) & ((unsigned)ix < 32u);
        const float vv = x[ok ? (c * 1024 + iy * 32 + ix) : 0];
        xs[e] = ok ? vv : 0.f;
    }
    __syncthreads();

    // ---- main loop: wave-pair wp owns chunks [wp*18, wp*18+18) for ALL 4 px.
    // W loads coalesced from wt4 (WT) or scattered from w (fallback),
    // register ping-pong wc/wn, zero barriers.
    const float4* wrow = (const float4*)(w + oc * CKK_);

    auto load8 = [&](float4* dst, int j) {
#pragma unroll
        for (int k4 = 0; k4 < 8; ++k4)
            dst[k4] = WT ? wt4[(j * 8 + k4) * 128 + oc] : wrow[j * 8 + k4];
    };

    auto chunk = [&](int j, const float4* wreg) {
        float a0 = 0.f, a1 = 0.f, a2 = 0.f, a3 = 0.f;
        const float4* xj = (const float4*)(xs + j * 128);  // [tap] -> 4 px
#pragma unroll
        for (int k4 = 0; k4 < 8; ++k4) {
            const float4 wv = wreg[k4];
            const float4 x0 = xj[4 * k4 + 0];
            const float4 x1 = xj[4 * k4 + 1];
            const float4 x2 = xj[4 * k4 + 2];
            const float4 x3 = xj[4 * k4 + 3];
            a0 = fmaf(wv.x, x0.x, a0); a1 = fmaf(wv.x, x0.y, a1);
            a2 = fmaf(wv.x, x0.z, a2); a3 = fmaf(wv.x, x0.w, a3);
            a0 = fmaf(wv.y, x1.x, a0); a1 = fmaf(wv.y, x1.y, a1);
            a2 = fmaf(wv.y, x1.z, a2); a3 = fmaf(wv.y, x1.w, a3);
            a0 = fmaf(wv.z, x2.x, a0); a1 = fmaf(wv.z, x2.y, a1);
            a2 = fmaf(wv.z, x2.z, a2); a3 = fmaf(wv.z, x2.w, a3);
            a0 = fmaf(wv.w, x3.x, a0); a1 = fmaf(wv.w, x3.y, a1);
            a2 = fmaf(wv.w, x3.z, a2); a3 = fmaf(wv.w, x3.w, a3);
        }
        vbuf[j][oc] = make_float4(a0, a1, a2, a3);   // thread-private slot
    };

    {
        const int jb = wp * 18;
        float4 wc[8], wn[8];
        load8(wc, jb);
        for (int jj = 0; jj < 18; jj += 2) {
            const int j0 = jb + jj;
            load8(wn, j0 + 1);              // prefetch while computing j0
            chunk(j0, wc);
            if (jj + 2 < 18) load8(wc, j0 + 2);
            chunk(j0 + 1, wn);
        }
    }
    __syncthreads();   // vbuf complete across wave-pairs

    // ---- totals: exact R5 summation order (j ascending, then +bias) ----
    // pp selects px pair {2pp, 2pp+1} = float4 components {x,y} or {z,w};
    // pp is wave-uniform -> uniform select, no divergence.
    float s0 = 0.f, s1 = 0.f;
    for (int j = 0; j < NCH; ++j) {
        const float4 vv = vbuf[j][oc];
        s0 += (pp == 0) ? vv.x : vv.z;
        s1 += (pp == 0) ? vv.y : vv.w;
    }
    const float bval = bias[oc];
    const float t0 = s0 + bval, t1 = s1 + bval;

    // ---- minmax + scale/zp (verbatim R5, verified) ----
    float mn0 = t0, mx0 = t0, mn1 = t1, mx1 = t1;
#pragma unroll
    for (int off = 32; off > 0; off >>= 1) {
        mn0 = fminf(mn0, __shfl_xor(mn0, off));
        mx0 = fmaxf(mx0, __shfl_xor(mx0, off));
        mn1 = fminf(mn1, __shfl_xor(mn1, off));
        mx1 = fmaxf(mx1, __shfl_xor(mx1, off));
    }
    const int wv = t >> 6;
    if ((t & 63) == 0) {
        red[wv][0] = mn0; red[wv][1] = mx0;
        red[wv][2] = mn1; red[wv][3] = mx1;
    }
    __syncthreads();
    if ((t & 63) == 0 && (wv & 1) == 0) {   // waves 0,2 finalize px pair pp
        const int pw = wv ^ 1;
        const float amn0 = fminf(mn0, red[pw][0]);
        const float amx0 = fmaxf(mx0, red[pw][1]);
        const float amn1 = fminf(mn1, red[pw][2]);
        const float amx1 = fmaxf(mx1, red[pw][3]);
        {
            const float sv = (amx0 - amn0) / QMAX_;
            float z = -amn0 / sv;
            z = fmaxf(z, 0.f);      // fmaxf(NaN,0)=0 matches where(isnan,0)
            z = fminf(z, QMAX_);
            z = truncf(z);
            spar[pp][0][0] = sv; spar[pp][0][1] = z; spar[pp][0][2] = 1.0f / sv;
        }
        {
            const float sv = (amx1 - amn1) / QMAX_;
            float z = -amn1 / sv;
            z = fmaxf(z, 0.f);
            z = fminf(z, QMAX_);
            z = truncf(z);
            spar[pp][1][0] = sv; spar[pp][1][1] = z; spar[pp][1][2] = 1.0f / sv;
        }
    }
    __syncthreads();

    // ---- fake-quant accumulate (j ascending, same ops as R5) ----
    const float sc0 = spar[pp][0][0], zp0 = spar[pp][0][1], iv0 = spar[pp][0][2];
    const float sc1 = spar[pp][1][0], zp1 = spar[pp][1][1], iv1 = spar[pp][1][2];
    float q0 = 0.f, q1 = 0.f;
    for (int j = 0; j < NCH; ++j) {
        const float4 vv = vbuf[j][oc];
        const float v0 = (pp == 0) ? vv.x : vv.z;
        const float v1 = (pp == 0) ? vv.y : vv.w;
        float qn0 = rintf(v0 * iv0) + zp0;   // rintf == round-half-even
        qn0 = fminf(fmaxf(qn0, 0.f), QMAX_);
        q0 += (qn0 - zp0) * sc0;
        float qn1 = rintf(v1 * iv1) + zp1;
        qn1 = fminf(fmaxf(qn1, 0.f), QMAX_);
        q1 += (qn1 - zp1) * sc1;
    }
    qb[2 * pp + 0][oc] = q0;
    qb[2 * pp + 1][oc] = q1;
    __syncthreads();

    if (t < 128)
        *(float4*)(out + (size_t)t * L_ + l0) =
            make_float4(qb[0][t], qb[1][t], qb[2][t], qb[3][t]);
}

extern "C" void kernel_launch(void* const* d_in, const int* in_sizes, int n_in,
                              void* d_out, int out_size, void* d_ws, size_t ws_size,
                              hipStream_t stream) {
    const float* x    = (const float*)d_in[0];  // 128*32*32
    const float* w    = (const float*)d_in[1];  // 128*1152
    const float* bias = (const float*)d_in[2];  // 128
    float* out = (float*)d_out;                 // 128*1024
    float* ws  = (float*)d_ws;

    const size_t wt_need = (size_t)288 * 128 * 16;   // 576 KB
    if (ws_size >= wt_need) {
        wtrans<<<144, 256, 0, stream>>>((const float*)d_in[1], ws);
        fused_cas<true><<<256, 256, 0, stream>>>(
            x, w, (const float4*)ws, bias, out);
    } else {
        fused_cas<false><<<256, 256, 0, stream>>>(
            x, w, nullptr, bias, out);
    }
}

// Round 7
// 69.481 us; speedup vs baseline: 7.9799x; 1.0868x over previous
//
#include <hip/hip_runtime.h>

// casConv2d: B=1, C=128, H=W=32, OC=128, K=3, pad=1, stride=1.
// L = 1024, CKK = 1152 = 36 exact 32-tap chunks (reference front-pad chunk == 0).
//
// Round-15. R6 post-mortem: coalesced W (wt4) + dedup got fused to ~21us
// (differential vs R5: 92.6-75.5 with fused_R5=40.7 -> fused_R6+wtrans~23.5).
// Issue model says ~6-7us; the 4x gap is exposed latency at 1 wave/SIMD
// (93KB LDS -> 1 block/CU; grid 256 -> 4 waves/CU). No second wave per SIMD
// to hide LDS-broadcast (~120cy) / L2 (~200cy) stalls.
//
// R7: 512-thread blocks, SAME 256-block grid (W-reuse/L2 budget unchanged):
// 8 waves/block = 2 waves/SIMD. Wave-pair group g=t>>7 owns 9 chunks
// (4 groups x 9 = 36), each group covers all 128 oc -> W reads stay
// coalesced, zero duplication. vbuf per-chunk partials and the R6-verified
// epilogue unchanged (threads 0-255 run it; 256-511 compute duplicates,
// gated off red/spar writes) -> bit-identical numerics, absmax 0.03515625.
#define L_    1024
#define CKK_  1152
#define QMAX_ 255.0f
#define NCH   36

// ---- W transpose: w[oc][1152] -> wt4[tq][oc] (tq = tap quad, 288x128 f4) ----
__global__ __launch_bounds__(256) void wtrans(
    const float* __restrict__ w, float* __restrict__ wt)
{
    const int e  = blockIdx.x * 256 + threadIdx.x;   // 36864 float4 slots
    const int oc = e / 288, tq = e - 288 * oc;
    const float4 v = ((const float4*)(w + oc * CKK_))[tq];   // coalesced read
    ((float4*)wt)[tq * 128 + oc] = v;                        // scattered write (L2)
}

template <bool WT>
__global__ __launch_bounds__(512) void fused_cas(
    const float* __restrict__ x,      // [128][32][32]
    const float* __restrict__ w,      // [128][1152]        (WT=false path)
    const float4* __restrict__ wt4,   // [288][128] float4  (WT=true path)
    const float* __restrict__ bias,   // [128]
    float* __restrict__ out)          // [128][1024]
{
    __shared__ __align__(16) float  xs[NCH * 32 * 4];   // [j][tap][px], 18 KB
    __shared__ __align__(16) float4 vbuf[NCH][128];     // [j][oc] px0..3, 72 KB
    __shared__ float red[8][4];                         // per-wave {mn0,mx0,mn1,mx1}
    __shared__ float spar[2][2][3];                     // [ppe][s]{sc,zp,iv}
    __shared__ float qb[4][128];                        // [px-local][oc]

    const int t   = threadIdx.x;                        // 0..511
    const int b   = blockIdx.x;
    const int oc  = t & 127;
    const int g   = t >> 7;            // chunk-ownership group (4 x 2 waves)
    const int ppe = g & 1;             // epilogue px-pair (threads 0..255)
    const int oh  = b >> 3;            // all 4 px share one output row
    const int ow0 = (b & 7) * 4;
    const int l0  = b * 4;

    // ---- prologue: stage ALL x for this block (4608 elems = 9/thread) ----
    for (int i = 0; i < 9; ++i) {
        const int e   = i * 512 + t;
        const int j   = e >> 7;            // chunk
        const int tap = (e >> 2) & 31;
        const int px  = e & 3;
        const int d   = j * 32 + tap;
        const int c   = d / 9, r = d - 9 * c;
        const int kh  = r / 3, kw = r - 3 * kh;
        const int iy  = oh + kh - 1, ix = ow0 + px + kw - 1;
        const bool ok = ((unsigned)iy < 32u) & ((unsigned)ix < 32u);
        const float vv = x[ok ? (c * 1024 + iy * 32 + ix) : 0];
        xs[e] = ok ? vv : 0.f;
    }
    __syncthreads();

    // ---- main loop: group g owns chunks [9g, 9g+9) for ALL 4 px ----
    const float4* wrow = (const float4*)(w + oc * CKK_);

    auto load8 = [&](float4* dst, int j) {
#pragma unroll
        for (int k4 = 0; k4 < 8; ++k4)
            dst[k4] = WT ? wt4[(j * 8 + k4) * 128 + oc] : wrow[j * 8 + k4];
    };

    auto chunk = [&](int j, const float4* wreg) {
        float a0 = 0.f, a1 = 0.f, a2 = 0.f, a3 = 0.f;
        const float4* xj = (const float4*)(xs + j * 128);  // [tap] -> 4 px
#pragma unroll
        for (int k4 = 0; k4 < 8; ++k4) {
            const float4 wv = wreg[k4];
            const float4 x0 = xj[4 * k4 + 0];
            const float4 x1 = xj[4 * k4 + 1];
            const float4 x2 = xj[4 * k4 + 2];
            const float4 x3 = xj[4 * k4 + 3];
            a0 = fmaf(wv.x, x0.x, a0); a1 = fmaf(wv.x, x0.y, a1);
            a2 = fmaf(wv.x, x0.z, a2); a3 = fmaf(wv.x, x0.w, a3);
            a0 = fmaf(wv.y, x1.x, a0); a1 = fmaf(wv.y, x1.y, a1);
            a2 = fmaf(wv.y, x1.z, a2); a3 = fmaf(wv.y, x1.w, a3);
            a0 = fmaf(wv.z, x2.x, a0); a1 = fmaf(wv.z, x2.y, a1);
            a2 = fmaf(wv.z, x2.z, a2); a3 = fmaf(wv.z, x2.w, a3);
            a0 = fmaf(wv.w, x3.x, a0); a1 = fmaf(wv.w, x3.y, a1);
            a2 = fmaf(wv.w, x3.z, a2); a3 = fmaf(wv.w, x3.w, a3);
        }
        vbuf[j][oc] = make_float4(a0, a1, a2, a3);   // group-private slot
    };

    {
        const int jb = g * 9;
        float4 wc[8], wn[8];
        load8(wc, jb);
#pragma unroll
        for (int jj = 0; jj < 8; jj += 2) {
            const int j0 = jb + jj;
            load8(wn, j0 + 1);              // prefetch while computing j0
            chunk(j0, wc);
            load8(wc, j0 + 2);              // jj<=6 -> jb+8 valid
            chunk(j0 + 1, wn);
        }
        chunk(jb + 8, wc);                  // tail (9th chunk)
    }
    __syncthreads();   // vbuf complete across groups

    // ---- totals: exact R5/R6 summation order (j ascending, then +bias).
    // Threads 256-511 compute benign duplicates of threads 0-255.
    float s0 = 0.f, s1 = 0.f;
    for (int j = 0; j < NCH; ++j) {
        const float4 vv = vbuf[j][oc];
        s0 += (ppe == 0) ? vv.x : vv.z;
        s1 += (ppe == 0) ? vv.y : vv.w;
    }
    const float bval = bias[oc];
    const float t0 = s0 + bval, t1 = s1 + bval;

    // ---- minmax + scale/zp (verbatim R6, verified) ----
    float mn0 = t0, mx0 = t0, mn1 = t1, mx1 = t1;
#pragma unroll
    for (int off = 32; off > 0; off >>= 1) {
        mn0 = fminf(mn0, __shfl_xor(mn0, off));
        mx0 = fmaxf(mx0, __shfl_xor(mx0, off));
        mn1 = fminf(mn1, __shfl_xor(mn1, off));
        mx1 = fmaxf(mx1, __shfl_xor(mx1, off));
    }
    const int wv = t >> 6;                  // 0..7
    if ((t & 63) == 0) {
        red[wv][0] = mn0; red[wv][1] = mx0;
        red[wv][2] = mn1; red[wv][3] = mx1;
    }
    __syncthreads();
    if ((t & 63) == 0 && (wv & 1) == 0 && wv < 4) {  // waves 0,2 finalize ppe
        const int pw = wv ^ 1;
        const float amn0 = fminf(mn0, red[pw][0]);
        const float amx0 = fmaxf(mx0, red[pw][1]);
        const float amn1 = fminf(mn1, red[pw][2]);
        const float amx1 = fmaxf(mx1, red[pw][3]);
        {
            const float sv = (amx0 - amn0) / QMAX_;
            float z = -amn0 / sv;
            z = fmaxf(z, 0.f);      // fmaxf(NaN,0)=0 matches where(isnan,0)
            z = fminf(z, QMAX_);
            z = truncf(z);
            spar[ppe][0][0] = sv; spar[ppe][0][1] = z; spar[ppe][0][2] = 1.0f / sv;
        }
        {
            const float sv = (amx1 - amn1) / QMAX_;
            float z = -amn1 / sv;
            z = fmaxf(z, 0.f);
            z = fminf(z, QMAX_);
            z = truncf(z);
            spar[ppe][1][0] = sv; spar[ppe][1][1] = z; spar[ppe][1][2] = 1.0f / sv;
        }
    }
    __syncthreads();

    // ---- fake-quant accumulate (j ascending, same ops as R6) ----
    const float sc0 = spar[ppe][0][0], zp0 = spar[ppe][0][1], iv0 = spar[ppe][0][2];
    const float sc1 = spar[ppe][1][0], zp1 = spar[ppe][1][1], iv1 = spar[ppe][1][2];
    float q0 = 0.f, q1 = 0.f;
    for (int j = 0; j < NCH; ++j) {
        const float4 vv = vbuf[j][oc];
        const float v0 = (ppe == 0) ? vv.x : vv.z;
        const float v1 = (ppe == 0) ? vv.y : vv.w;
        float qn0 = rintf(v0 * iv0) + zp0;   // rintf == round-half-even
        qn0 = fminf(fmaxf(qn0, 0.f), QMAX_);
        q0 += (qn0 - zp0) * sc0;
        float qn1 = rintf(v1 * iv1) + zp1;
        qn1 = fminf(fmaxf(qn1, 0.f), QMAX_);
        q1 += (qn1 - zp1) * sc1;
    }
    if (t < 256) {
        qb[2 * ppe + 0][oc] = q0;
        qb[2 * ppe + 1][oc] = q1;
    }
    __syncthreads();

    if (t < 128)
        *(float4*)(out + (size_t)t * L_ + l0) =
            make_float4(qb[0][t], qb[1][t], qb[2][t], qb[3][t]);
}

extern "C" void kernel_launch(void* const* d_in, const int* in_sizes, int n_in,
                              void* d_out, int out_size, void* d_ws, size_t ws_size,
                              hipStream_t stream) {
    const float* x    = (const float*)d_in[0];  // 128*32*32
    const float* w    = (const float*)d_in[1];  // 128*1152
    const float* bias = (const float*)d_in[2];  // 128
    float* out = (float*)d_out;                 // 128*1024
    float* ws  = (float*)d_ws;

    const size_t wt_need = (size_t)288 * 128 * 16;   // 576 KB
    if (ws_size >= wt_need) {
        wtrans<<<144, 256, 0, stream>>>((const float*)d_in[1], ws);
        fused_cas<true><<<256, 512, 0, stream>>>(
            x, w, (const float4*)ws, bias, out);
    } else {
        fused_cas<false><<<256, 512, 0, stream>>>(
            x, w, nullptr, bias, out);
    }
}